// Round 4
// baseline (393.930 us; speedup 1.0000x reference)
//
#include <hip/hip_runtime.h>
#include <hip/hip_bf16.h>
#include <hip/hip_fp16.h>

// Problem constants (from setup_inputs): B=4, T=4096, D=1024, H=1024
#define B_ 4
#define T_ 4096
#define D_ 1024
#define H_ 1024
#define M_ (B_ * T_)   // 16384

typedef __attribute__((ext_vector_type(8))) short short8;   // 8 bf16 = 4 VGPRs (MFMA A/B frag)
typedef __attribute__((ext_vector_type(4))) float f32x4;    // MFMA C/D frag

// ---------------- fp32 -> bf16 (RNE) ----------------
__device__ __forceinline__ unsigned short f2bf(float f) {
    unsigned int u = __float_as_uint(f);
    u += 0x7fffu + ((u >> 16) & 1u);
    return (unsigned short)(u >> 16);
}

// One kernel converts x, Wz, Wh (ranges concatenated).
__global__ __launch_bounds__(256) void convert_all(
    const float* __restrict__ x, const float* __restrict__ wz, const float* __restrict__ wh,
    unsigned short* __restrict__ xb, unsigned short* __restrict__ wzb, unsigned short* __restrict__ whb)
{
    int i = blockIdx.x * 256 + threadIdx.x;
    const float* s; unsigned short* d; int off;
    if (i < 4194304)      { s = x;  d = xb;  off = i; }
    else if (i < 4456448) { s = wz; d = wzb; off = i - 4194304; }
    else                  { s = wh; d = whb; off = i - 4456448; }
    float4 f = ((const float4*)s)[off];
    ushort4 u;
    u.x = f2bf(f.x); u.y = f2bf(f.y); u.z = f2bf(f.z); u.w = f2bf(f.w);
    ((ushort4*)d)[off] = u;
}

// ---------------- fused dual GEMM + epilogue + chunk-summary (NO LDS, NO BARRIERS) ----------------
// Block tile 128(M) x 64(N); 4 waves; wave w: whalf=w>>1 (64 rows), nhalf=w&1 (32 cols).
// MFMA 16x16x32 bf16, BK=32. Each lane's fragment = 16 contiguous global bytes:
//   A[m = lane&15][k = (lane>>4)*8 + j]  ->  row (group*16 + r16), bytes [kk + q*8 .. +7]
// so fragments are loaded straight global->VGPR (dwordx4), register double-buffered.
// No __syncthreads in the K-loop => compiler emits fine-grained vmcnt(N) pipelining
// (AITER-style) instead of a full vmcnt(0) drain per iteration.
// Epilogue: a=sigmoid(-k), v=sigmoid(k)*g(hb) -> av16 half2(a,v); per-64-chunk affine
// composition -> chunkAV.
__global__ __launch_bounds__(256, 3) void dual_gemm_kernel(
    const unsigned short* __restrict__ xb,   // [M][D] bf16
    const unsigned short* __restrict__ wzb,  // [H][D] bf16
    const unsigned short* __restrict__ whb,  // [H][D] bf16
    const float* __restrict__ bz,
    const float* __restrict__ bh,
    __half2* __restrict__ av16,              // [M][H] half2(a,v)
    float2* __restrict__ chunkAV)            // [64][B][H]
{
    const int tid   = threadIdx.x;
    const int lane  = tid & 63;
    const int w     = tid >> 6;
    const int whalf = w >> 1;
    const int nhalf = w & 1;
    const int nb    = blockIdx.x >> 7;       // 0..15  (nb-major: consecutive blocks share B)
    const int mb    = blockIdx.x & 127;      // 0..127
    const int r16   = lane & 15;
    const int q     = lane >> 4;

    // per-lane fragment base pointers (each + kk gives this lane's 16B fragment)
    const unsigned short* gA[4];
    const unsigned short* gBz[2];
    const unsigned short* gBh[2];
#pragma unroll
    for (int gm = 0; gm < 4; ++gm)
        gA[gm] = xb + (size_t)(mb * 128 + whalf * 64 + gm * 16 + r16) * D_ + q * 8;
#pragma unroll
    for (int gn = 0; gn < 2; ++gn) {
        gBz[gn] = wzb + (size_t)(nb * 64 + nhalf * 32 + gn * 16 + r16) * D_ + q * 8;
        gBh[gn] = whb + (size_t)(nb * 64 + nhalf * 32 + gn * 16 + r16) * D_ + q * 8;
    }

    f32x4 accz[4][2] = {};
    f32x4 acch[4][2] = {};

    short8 fa0[4], fz0[2], fh0[2];
    short8 fa1[4], fz1[2], fh1[2];

#define LOADF(fa, fz, fh, off) do {                                              \
    _Pragma("unroll") for (int i_ = 0; i_ < 4; ++i_)                             \
        fa[i_] = *(const short8*)(gA[i_] + (off));                               \
    _Pragma("unroll") for (int i_ = 0; i_ < 2; ++i_) {                           \
        fz[i_] = *(const short8*)(gBz[i_] + (off));                              \
        fh[i_] = *(const short8*)(gBh[i_] + (off));                              \
    } } while (0)

#define MFMAS(fa, fz, fh) do {                                                   \
    _Pragma("unroll") for (int gm_ = 0; gm_ < 4; ++gm_)                          \
    _Pragma("unroll") for (int gn_ = 0; gn_ < 2; ++gn_) {                        \
        accz[gm_][gn_] = __builtin_amdgcn_mfma_f32_16x16x32_bf16(fa[gm_], fz[gn_], accz[gm_][gn_], 0, 0, 0); \
        acch[gm_][gn_] = __builtin_amdgcn_mfma_f32_16x16x32_bf16(fa[gm_], fh[gn_], acch[gm_][gn_], 0, 0, 0); \
    } } while (0)

    LOADF(fa0, fz0, fh0, 0);
#pragma unroll 4
    for (int kk = 0; kk < D_; kk += 64) {
        LOADF(fa1, fz1, fh1, kk + 32);       // prefetch next half-iter
        MFMAS(fa0, fz0, fh0);
        LOADF(fa0, fz0, fh0, kk + 64);       // prefetch next iter (last one overshoots 64B into ws; harmless, dead)
        MFMAS(fa1, fz1, fh1);
    }
#undef LOADF
#undef MFMAS

    // Epilogue. C/D layout: col = lane&15, row = q*4 + rr  [verified m89/m91]
    const int cglob = mb * 2 + whalf;        // global 64-row chunk id, 0..255
    const int cc = cglob & 63;
    const int bb = cglob >> 6;
#pragma unroll
    for (int gn = 0; gn < 2; ++gn) {
        const int ncol = nb * 64 + nhalf * 32 + gn * 16 + r16;
        const float bzv = bz[ncol];
        const float bhv = bh[ncol];
        float CA = 1.0f, CV = 0.0f;          // chunk composite
#pragma unroll
        for (int gm = 0; gm < 4; ++gm) {
            float LA = 1.0f, LV = 0.0f;      // this lane's 4-row segment
#pragma unroll
            for (int rr = 0; rr < 4; ++rr) {
                float kv = accz[gm][gn][rr] + bzv;
                float hv = acch[gm][gn][rr] + bhv;
                float tk = __expf(-fabsf(kv));
                float ik = 1.0f / (1.0f + tk);
                float sig = (kv >= 0.0f) ? ik : tk * ik;         // sigmoid(k)
                float ac  = (kv >= 0.0f) ? tk * ik : ik;         // sigmoid(-k)
                float th = __expf(-fabsf(hv));
                float ih = 1.0f / (1.0f + th);
                float gh = (hv >= 0.0f) ? (hv + 0.5f) : th * ih; // g(hb)
                float vv = sig * gh;
                const size_t m = (size_t)mb * 128 + whalf * 64 + gm * 16 + q * 4 + rr;
                av16[(size_t)m * H_ + ncol] = __floats2half2_rn(ac, vv);
                LV = ac * LV + vv;           // ascending t composition
                LA = ac * LA;
            }
            // order-preserving combine across q (lower lane index = earlier segment)
#pragma unroll
            for (int mask = 16; mask <= 32; mask <<= 1) {
                float PA = __shfl_xor(LA, mask);
                float PV = __shfl_xor(LV, mask);
                if (lane & mask) { LV = LA * PV + LV; LA = LA * PA; }
                else             { LV = PA * LV + PV; LA = PA * LA; }
            }
            CV = LA * CV + LV;
            CA = LA * CA;
        }
        if (q == 0)
            chunkAV[cc * 4096 + bb * 1024 + ncol] = make_float2(CA, CV);
    }
}

// ---------------- scan pass2: sequential over 64 chunk summaries per channel ----------------
__global__ __launch_bounds__(256) void scan_pass2(const float2* __restrict__ chunkAV,
                                                  const float* __restrict__ h0,
                                                  float* __restrict__ hstart) {
    int chan = blockIdx.x * blockDim.x + threadIdx.x;   // 4096 threads
    int n = chan & (H_ - 1);
    int b = chan >> 10;
    float x = h0[b * H_ + n];
    float h;
    if (x >= 0.0f) { h = x + 0.5f; }
    else { float t = __expf(x); h = t / (1.0f + t); }   // g(h0)
#pragma unroll 8
    for (int c = 0; c < 64; ++c) {
        hstart[c * 4096 + chan] = h;
        float2 s = chunkAV[c * 4096 + chan];
        h = s.x * h + s.y;
    }
}

// ---------------- scan pass3: replay each chunk from entry state ----------------
__global__ __launch_bounds__(256) void scan_pass3(const __half2* __restrict__ av16,
                                                  const float* __restrict__ hstart,
                                                  float* __restrict__ out) {
    int g = blockIdx.x * blockDim.x + threadIdx.x;
    int n = g & (H_ - 1);
    int rest = g >> 10;
    int c = rest & 63;
    int b = rest >> 6;
    float h = hstart[c * 4096 + b * 1024 + n];
    const __half2* base = av16 + ((size_t)(b * T_ + c * 64)) * H_ + n;
    float* obase = out + ((size_t)(b * T_ + c * 64)) * H_ + n;
#pragma unroll 8
    for (int t = 0; t < 64; ++t) {
        float2 p = __half22float2(base[(size_t)t * H_]);
        h = p.x * h + p.y;
        obase[(size_t)t * H_] = h;
    }
}

// ---------------- launch ----------------
extern "C" void kernel_launch(void* const* d_in, const int* in_sizes, int n_in,
                              void* d_out, int out_size, void* d_ws, size_t ws_size,
                              hipStream_t stream) {
    const float* x  = (const float*)d_in[0];   // [B,T,D]
    const float* h0 = (const float*)d_in[1];   // [B,H]
    const float* Wz = (const float*)d_in[2];   // [H,D]
    const float* bz = (const float*)d_in[3];   // [H]
    const float* Wh = (const float*)d_in[4];   // [H,D]
    const float* bh = (const float*)d_in[5];   // [H]
    float* out = (float*)d_out;

    // workspace layout (bytes):
    //   xb  bf16 [M][D]            @ 0            33,554,432
    //   wzb bf16 [H][D]            @ 33554432      2,097,152
    //   whb bf16 [H][D]            @ 35651584      2,097,152
    //   av16 half2 [M][H]          @ 37748736     67,108,864
    //   chunkAV float2 [64][B][H]  @ 104857600     2,097,152
    //   hstart fp32 [64][B*H]      @ 106954752     1,048,576
    char* ws = (char*)d_ws;
    unsigned short* xb  = (unsigned short*)(ws);
    unsigned short* wzb = (unsigned short*)(ws + 33554432);
    unsigned short* whb = (unsigned short*)(ws + 35651584);
    __half2* av16       = (__half2*)(ws + 37748736);
    float2* chunkAV     = (float2*)(ws + 104857600);
    float*  hstart      = (float*)(ws + 106954752);

    convert_all<<<18432, 256, 0, stream>>>(x, Wz, Wh, xb, wzb, whb);

    dual_gemm_kernel<<<2048, 256, 0, stream>>>(xb, wzb, whb, bz, bh, av16, chunkAV);

    scan_pass2<<<16,   256, 0, stream>>>(chunkAV, h0, hstart);
    scan_pass3<<<1024, 256, 0, stream>>>(av16, hstart, out);
}

// Round 5
// 285.375 us; speedup vs baseline: 1.3804x; 1.3804x over previous
//
#include <hip/hip_runtime.h>
#include <hip/hip_bf16.h>
#include <hip/hip_fp16.h>

// Problem constants (from setup_inputs): B=4, T=4096, D=1024, H=1024
#define B_ 4
#define T_ 4096
#define D_ 1024
#define H_ 1024
#define M_ (B_ * T_)   // 16384

typedef __attribute__((ext_vector_type(8))) short short8;   // 8 bf16 = 4 VGPRs (MFMA A/B frag)
typedef __attribute__((ext_vector_type(4))) float f32x4;    // MFMA C/D frag

// ---------------- fp32 -> bf16 (RNE) ----------------
__device__ __forceinline__ unsigned short f2bf(float f) {
    unsigned int u = __float_as_uint(f);
    u += 0x7fffu + ((u >> 16) & 1u);
    return (unsigned short)(u >> 16);
}

// One kernel converts x, Wz, Wh (ranges concatenated).
__global__ __launch_bounds__(256) void convert_all(
    const float* __restrict__ x, const float* __restrict__ wz, const float* __restrict__ wh,
    unsigned short* __restrict__ xb, unsigned short* __restrict__ wzb, unsigned short* __restrict__ whb)
{
    int i = blockIdx.x * 256 + threadIdx.x;
    const float* s; unsigned short* d; int off;
    if (i < 4194304)      { s = x;  d = xb;  off = i; }
    else if (i < 4456448) { s = wz; d = wzb; off = i - 4194304; }
    else                  { s = wh; d = whb; off = i - 4456448; }
    float4 f = ((const float4*)s)[off];
    ushort4 u;
    u.x = f2bf(f.x); u.y = f2bf(f.y); u.z = f2bf(f.z); u.w = f2bf(f.w);
    ((ushort4*)d)[off] = u;
}

// async global->LDS, 16B per lane; LDS dest = wave-uniform base + lane*16
__device__ __forceinline__ void async16(const void* g, void* l) {
    __builtin_amdgcn_global_load_lds(
        (__attribute__((address_space(1))) void*)g,
        (__attribute__((address_space(3))) void*)l,
        16, 0, 0);
}

// ---------------- fused dual GEMM + epilogue + chunk-summary ----------------
// R2-proven structure, register-dieted for 4 waves/SIMD (4 blocks/CU):
// Block tile 128(M) x 64(N), BK=32, 4 waves; wave w: whalf=w>>1 (64 rows), nhalf=w&1 (32 cols).
// LDS fragment-order subtiles (16 rows x 32 k), 16 KB single-buffered, 2 barriers/iter.
// Staging: wave w -> A subtiles {2w,2w+1}, Bz subtile w, Bh subtile w (1 KB each, async16 x4).
// Compute: 8 ds_read_b128 + 16 MFMA per wave per iter.
// __launch_bounds__(256,4): unified budget 128/wave (64 acc AGPR + ~50 arch VGPR target).
__global__ __launch_bounds__(256, 4) void dual_gemm_kernel(
    const unsigned short* __restrict__ xb,   // [M][D] bf16
    const unsigned short* __restrict__ wzb,  // [H][D] bf16
    const unsigned short* __restrict__ whb,  // [H][D] bf16
    const float* __restrict__ bz,
    const float* __restrict__ bh,
    __half2* __restrict__ av16,              // [M][H] half2(a,v)
    float2* __restrict__ chunkAV)            // [64][B][H]
{
    __shared__ short8 ldsA[8 * 64];          // 8 KB
    __shared__ short8 ldsBz[4 * 64];         // 4 KB
    __shared__ short8 ldsBh[4 * 64];         // 4 KB

    const int tid   = threadIdx.x;
    const int lane  = tid & 63;
    const int w     = __builtin_amdgcn_readfirstlane(tid >> 6);  // force SGPR wave id
    const int whalf = w >> 1;
    const int nhalf = w & 1;
    const int nb    = blockIdx.x >> 7;       // 0..15  (nb-major: consecutive blocks share B)
    const int mb    = blockIdx.x & 127;      // 0..127
    const int r16   = lane & 15;
    const int q     = lane >> 4;

    // single lane-dependent element offset, shared by A and B staging
    const int laneoff = r16 * D_ + q * 8;    // 1 VGPR

    // wave-uniform global bases (SGPR) + shared lane offset (VGPR)
    const unsigned short* gA0 = xb  + (size_t)(mb * 128 + (2 * w) * 16) * D_ + laneoff;
    const unsigned short* gA1 = gA0 + 16 * D_;
    const unsigned short* gBz = wzb + (size_t)(nb * 64 + w * 16) * D_ + laneoff;
    const unsigned short* gBh = whb + (size_t)(nb * 64 + w * 16) * D_ + laneoff;
    short8* lA0 = &ldsA[(2 * w) * 64];       // wave-uniform LDS bases
    short8* lA1 = &ldsA[(2 * w + 1) * 64];
    short8* lBz = &ldsBz[w * 64];
    short8* lBh = &ldsBh[w * 64];

    f32x4 accz[4][2] = {};
    f32x4 acch[4][2] = {};

    for (int kk = 0; kk < D_; kk += 32) {
        __syncthreads();                     // prior iter's ds_reads complete (WAR)
        async16(gA0 + kk, lA0);
        async16(gA1 + kk, lA1);
        async16(gBz + kk, lBz);
        async16(gBh + kk, lBh);
        __syncthreads();                     // staged data visible

        short8 fa[4], fz[2], fh[2];
#pragma unroll
        for (int gm = 0; gm < 4; ++gm) fa[gm] = ldsA[(whalf * 4 + gm) * 64 + lane];
#pragma unroll
        for (int gn = 0; gn < 2; ++gn) {
            fz[gn] = ldsBz[(nhalf * 2 + gn) * 64 + lane];
            fh[gn] = ldsBh[(nhalf * 2 + gn) * 64 + lane];
        }
#pragma unroll
        for (int gm = 0; gm < 4; ++gm)
#pragma unroll
            for (int gn = 0; gn < 2; ++gn) {
                accz[gm][gn] = __builtin_amdgcn_mfma_f32_16x16x32_bf16(fa[gm], fz[gn], accz[gm][gn], 0, 0, 0);
                acch[gm][gn] = __builtin_amdgcn_mfma_f32_16x16x32_bf16(fa[gm], fh[gn], acch[gm][gn], 0, 0, 0);
            }
    }

    // Epilogue. C/D layout: col = lane&15, row = q*4 + rr  [verified m89/m91]
    const int cglob = mb * 2 + whalf;        // global 64-row chunk id, 0..255
    const int cc = cglob & 63;
    const int bb = cglob >> 6;
#pragma unroll
    for (int gn = 0; gn < 2; ++gn) {
        const int ncol = nb * 64 + nhalf * 32 + gn * 16 + r16;
        const float bzv = bz[ncol];
        const float bhv = bh[ncol];
        float CA = 1.0f, CV = 0.0f;          // chunk composite
#pragma unroll
        for (int gm = 0; gm < 4; ++gm) {
            float LA = 1.0f, LV = 0.0f;      // this lane's 4-row segment
#pragma unroll
            for (int rr = 0; rr < 4; ++rr) {
                float kv = accz[gm][gn][rr] + bzv;
                float hv = acch[gm][gn][rr] + bhv;
                float tk = __expf(-fabsf(kv));
                float ik = 1.0f / (1.0f + tk);
                float sig = (kv >= 0.0f) ? ik : tk * ik;         // sigmoid(k)
                float ac  = (kv >= 0.0f) ? tk * ik : ik;         // sigmoid(-k)
                float th = __expf(-fabsf(hv));
                float ih = 1.0f / (1.0f + th);
                float gh = (hv >= 0.0f) ? (hv + 0.5f) : th * ih; // g(hb)
                float vv = sig * gh;
                const size_t m = (size_t)mb * 128 + whalf * 64 + gm * 16 + q * 4 + rr;
                av16[(size_t)m * H_ + ncol] = __floats2half2_rn(ac, vv);
                LV = ac * LV + vv;           // ascending t composition
                LA = ac * LA;
            }
            // order-preserving combine across q (lower lane index = earlier segment)
#pragma unroll
            for (int mask = 16; mask <= 32; mask <<= 1) {
                float PA = __shfl_xor(LA, mask);
                float PV = __shfl_xor(LV, mask);
                if (lane & mask) { LV = LA * PV + LV; LA = LA * PA; }
                else             { LV = PA * LV + PV; LA = PA * LA; }
            }
            CV = LA * CV + LV;
            CA = LA * CA;
        }
        if (q == 0)
            chunkAV[cc * 4096 + bb * 1024 + ncol] = make_float2(CA, CV);
    }
}

// ---------------- scan pass2: sequential over 64 chunk summaries per channel ----------------
__global__ __launch_bounds__(256) void scan_pass2(const float2* __restrict__ chunkAV,
                                                  const float* __restrict__ h0,
                                                  float* __restrict__ hstart) {
    int chan = blockIdx.x * blockDim.x + threadIdx.x;   // 4096 threads
    int n = chan & (H_ - 1);
    int b = chan >> 10;
    float x = h0[b * H_ + n];
    float h;
    if (x >= 0.0f) { h = x + 0.5f; }
    else { float t = __expf(x); h = t / (1.0f + t); }   // g(h0)
#pragma unroll 8
    for (int c = 0; c < 64; ++c) {
        hstart[c * 4096 + chan] = h;
        float2 s = chunkAV[c * 4096 + chan];
        h = s.x * h + s.y;
    }
}

// ---------------- scan pass3: replay each chunk from entry state ----------------
__global__ __launch_bounds__(256) void scan_pass3(const __half2* __restrict__ av16,
                                                  const float* __restrict__ hstart,
                                                  float* __restrict__ out) {
    int g = blockIdx.x * blockDim.x + threadIdx.x;
    int n = g & (H_ - 1);
    int rest = g >> 10;
    int c = rest & 63;
    int b = rest >> 6;
    float h = hstart[c * 4096 + b * 1024 + n];
    const __half2* base = av16 + ((size_t)(b * T_ + c * 64)) * H_ + n;
    float* obase = out + ((size_t)(b * T_ + c * 64)) * H_ + n;
#pragma unroll 8
    for (int t = 0; t < 64; ++t) {
        float2 p = __half22float2(base[(size_t)t * H_]);
        h = p.x * h + p.y;
        obase[(size_t)t * H_] = h;
    }
}

// ---------------- launch ----------------
extern "C" void kernel_launch(void* const* d_in, const int* in_sizes, int n_in,
                              void* d_out, int out_size, void* d_ws, size_t ws_size,
                              hipStream_t stream) {
    const float* x  = (const float*)d_in[0];   // [B,T,D]
    const float* h0 = (const float*)d_in[1];   // [B,H]
    const float* Wz = (const float*)d_in[2];   // [H,D]
    const float* bz = (const float*)d_in[3];   // [H]
    const float* Wh = (const float*)d_in[4];   // [H,D]
    const float* bh = (const float*)d_in[5];   // [H]
    float* out = (float*)d_out;

    // workspace layout (bytes):
    //   xb  bf16 [M][D]            @ 0            33,554,432
    //   wzb bf16 [H][D]            @ 33554432      2,097,152
    //   whb bf16 [H][D]            @ 35651584      2,097,152
    //   av16 half2 [M][H]          @ 37748736     67,108,864
    //   chunkAV float2 [64][B][H]  @ 104857600     2,097,152
    //   hstart fp32 [64][B*H]      @ 106954752     1,048,576
    char* ws = (char*)d_ws;
    unsigned short* xb  = (unsigned short*)(ws);
    unsigned short* wzb = (unsigned short*)(ws + 33554432);
    unsigned short* whb = (unsigned short*)(ws + 35651584);
    __half2* av16       = (__half2*)(ws + 37748736);
    float2* chunkAV     = (float2*)(ws + 104857600);
    float*  hstart      = (float*)(ws + 106954752);

    convert_all<<<18432, 256, 0, stream>>>(x, Wz, Wh, xb, wzb, whb);

    dual_gemm_kernel<<<2048, 256, 0, stream>>>(xb, wzb, whb, bz, bh, av16, chunkAV);

    scan_pass2<<<16,   256, 0, stream>>>(chunkAV, h0, hstart);
    scan_pass3<<<1024, 256, 0, stream>>>(av16, hstart, out);
}